// Round 1
// baseline (244.587 us; speedup 1.0000x reference)
//
#include <hip/hip_runtime.h>
#include <stdint.h>

// ---- types ----
typedef short bf16x8 __attribute__((ext_vector_type(8)));   // 8 bf16 in 4 VGPRs
typedef float f32x4  __attribute__((ext_vector_type(4)));

__device__ __forceinline__ unsigned short f2bf(float f) {
    unsigned int u = __float_as_uint(f);
    u += 0x7FFFu + ((u >> 16) & 1u);   // round-to-nearest-even
    return (unsigned short)(u >> 16);
}
__device__ __forceinline__ float bf2f(unsigned short h) {
    return __uint_as_float(((unsigned int)h) << 16);
}

// ---- kernel A: fold W1f = w1@wf, W2f = w2@wf (store transposed, bf16), cb = b@wf ----
// grid: 2*129 blocks x 128 threads. block (mat,kk): kk<128 -> weight row, kk==128 -> bias row.
__global__ void fuse_weights(const float* __restrict__ w1, const float* __restrict__ b1,
                             const float* __restrict__ w2, const float* __restrict__ b2,
                             const float* __restrict__ wf,
                             unsigned short* __restrict__ wcT,  // [2][128 cols][128 k] bf16
                             float* __restrict__ cb)            // [2][128]
{
    int mat = blockIdx.x / 129;
    int kk  = blockIdx.x % 129;
    int c   = threadIdx.x;                 // 0..127 output col
    const float* w = (mat == 0) ? w1 : w2;
    const float* b = (mat == 0) ? b1 : b2;
    float acc = 0.f;
    if (kk < 128) {
        #pragma unroll 8
        for (int j = 0; j < 128; ++j) acc += w[kk * 128 + j] * wf[j * 128 + c];
        wcT[mat * 16384 + c * 128 + kk] = f2bf(acc);   // transposed: [col][k]
    } else {
        #pragma unroll 8
        for (int j = 0; j < 128; ++j) acc += b[j] * wf[j * 128 + c];
        cb[mat * 128 + c] = acc;
    }
}

// ---- kernel B: g[mat] = x @ Wc[mat] + cb[mat], stored bf16 row-major [nrows][128] ----
// 256 thr = 4 waves; each wave does 32 x-rows. D = A(W^T tile) * B(x^T tile):
//   A-frag: lane l holds A[(l&15)][ (l>>4)*8 + i ]  (M=wcol, K)
//   B-frag: lane l holds B[ (l>>4)*8 + i ][ l&15 ]  = x[xrow=l&15][k]
//   D:      col = lane&15 = xrow, row = (lane>>4)*4 + reg = wcol  -> 4 consecutive wcols/lane
#define WAVE_ROWS 32
__global__ __launch_bounds__(256) void gemm_g(
    const float* __restrict__ x, const unsigned short* __restrict__ wcT,
    const float* __restrict__ cb, unsigned short* __restrict__ g, int nrows)
{
    int lane = threadIdx.x & 63;
    int wid  = threadIdx.x >> 6;
    int r0   = (blockIdx.x * 4 + wid) * WAVE_ROWS;
    if (r0 >= nrows) return;
    int lrow = lane & 15;
    int kg   = lane >> 4;

    // load + convert x fragments: xf[t][ks], t = rowtile(2), ks = kstep(4)
    bf16x8 xf[2][4];
    #pragma unroll
    for (int t = 0; t < 2; ++t) {
        int row  = r0 + t * 16 + lrow;
        bool v   = row < nrows;
        #pragma unroll
        for (int ks = 0; ks < 4; ++ks) {
            int k0 = ks * 32 + kg * 8;
            float4 p0 = v ? *(const float4*)(x + (size_t)row * 128 + k0)     : float4{0,0,0,0};
            float4 p1 = v ? *(const float4*)(x + (size_t)row * 128 + k0 + 4) : float4{0,0,0,0};
            bf16x8 f;
            f[0] = (short)f2bf(p0.x); f[1] = (short)f2bf(p0.y);
            f[2] = (short)f2bf(p0.z); f[3] = (short)f2bf(p0.w);
            f[4] = (short)f2bf(p1.x); f[5] = (short)f2bf(p1.y);
            f[6] = (short)f2bf(p1.z); f[7] = (short)f2bf(p1.w);
            xf[t][ks] = f;
        }
    }

    #pragma unroll
    for (int mat = 0; mat < 2; ++mat) {
        unsigned short* gm = g + (size_t)mat * nrows * 128;
        const unsigned short* wT = wcT + mat * 16384;
        for (int c = 0; c < 8; ++c) {                 // 8 col-tiles of 16
            bf16x8 wfr[4];
            const unsigned short* wb = wT + (size_t)(c * 16 + lrow) * 128 + kg * 8;
            #pragma unroll
            for (int ks = 0; ks < 4; ++ks)
                wfr[ks] = *(const bf16x8*)(wb + ks * 32);
            f32x4 acc0 = {0,0,0,0}, acc1 = {0,0,0,0};
            #pragma unroll
            for (int ks = 0; ks < 4; ++ks) {
                acc0 = __builtin_amdgcn_mfma_f32_16x16x32_bf16(wfr[ks], xf[0][ks], acc0, 0,0,0);
                acc1 = __builtin_amdgcn_mfma_f32_16x16x32_bf16(wfr[ks], xf[1][ks], acc1, 0,0,0);
            }
            float4 bias = *(const float4*)(cb + mat * 128 + c * 16 + kg * 4);
            #pragma unroll
            for (int t = 0; t < 2; ++t) {
                f32x4 a = (t == 0) ? acc0 : acc1;
                int xrow = r0 + t * 16 + lrow;
                if (xrow < nrows) {
                    ushort4 o;
                    o.x = f2bf(a[0] + bias.x); o.y = f2bf(a[1] + bias.y);
                    o.z = f2bf(a[2] + bias.z); o.w = f2bf(a[3] + bias.w);
                    *(ushort4*)(gm + (size_t)xrow * 128 + c * 16 + kg * 4) = o;
                }
            }
        }
    }
}

// ---- kernel C: gather + mask + bias -> out (f32) and mask (f32 0/1) ----
// one wave per output row (n,j); lane covers 2 of 128 dims.
__global__ __launch_bounds__(256) void gather_out(
    const int* __restrict__ ci, const unsigned short* __restrict__ g,
    const float* __restrict__ bfv, float* __restrict__ out,
    float* __restrict__ maskout, int nnodes, int rowstotal)
{
    int gw   = (int)((blockIdx.x * blockDim.x + threadIdx.x) >> 6);
    int lane = threadIdx.x & 63;
    if (gw >= rowstotal) return;
    unsigned int un = (unsigned int)gw / 7u;
    int n = (int)un;
    int j = gw - n * 7;

    int civ = ci[n * 8 + (lane & 7)];
    unsigned long long bal = __ballot(civ == -1);
    int cnt = __popcll(bal & 0xFFull);
    int deg = (cnt == 8) ? 0 : (7 - cnt);
    int i0 = __shfl(civ, j);
    int i1 = __shfl(civ, j + 1);
    bool m = (j < deg);

    int d = lane * 2;
    float s0 = 0.f, s1 = 0.f;
    if (m) {
        if (deg >= 1 && i0 >= 0 && i0 < nnodes) {
            unsigned int u = *(const unsigned int*)(g + (size_t)i0 * 128 + d);
            s0 += bf2f((unsigned short)(u & 0xFFFFu));
            s1 += bf2f((unsigned short)(u >> 16));
        }
        if (deg >= 2 && i1 >= 0 && i1 < nnodes) {
            unsigned int u = *(const unsigned int*)(g + (size_t)(nnodes + i1) * 128 + d);
            s0 += bf2f((unsigned short)(u & 0xFFFFu));
            s1 += bf2f((unsigned short)(u >> 16));
        }
    }
    float2 bfd = *(const float2*)(bfv + d);
    float2 o;
    o.x = s0 + bfd.x;
    o.y = s1 + bfd.y;
    *(float2*)(out + (size_t)gw * 128 + d) = o;
    if (lane == 0) maskout[gw] = m ? 1.0f : 0.0f;
}

extern "C" void kernel_launch(void* const* d_in, const int* in_sizes, int n_in,
                              void* d_out, int out_size, void* d_ws, size_t ws_size,
                              hipStream_t stream) {
    const float* x   = (const float*)d_in[0];
    const float* w1  = (const float*)d_in[1];
    const float* b1  = (const float*)d_in[2];
    const float* w2  = (const float*)d_in[3];
    const float* b2  = (const float*)d_in[4];
    const float* wf  = (const float*)d_in[5];
    const float* bfv = (const float*)d_in[6];
    const int*   ci  = (const int*)d_in[7];

    int nrows = in_sizes[0] / 128;                 // N = 100000

    // workspace layout: g (2 x N x 128 bf16) | wcT (2x128x128 bf16) | cb (2x128 f32)
    size_t gbytes = (size_t)2 * nrows * 128 * 2;
    unsigned short* g   = (unsigned short*)d_ws;
    unsigned short* wcT = (unsigned short*)((char*)d_ws + ((gbytes + 255) & ~(size_t)255));
    float*          cb  = (float*)((char*)wcT + 2 * 128 * 128 * 2);

    fuse_weights<<<2 * 129, 128, 0, stream>>>(w1, b1, w2, b2, wf, wcT, cb);

    int nblk = (nrows + 4 * WAVE_ROWS - 1) / (4 * WAVE_ROWS);
    gemm_g<<<nblk, 256, 0, stream>>>(x, wcT, cb, g, nrows);

    int rows = nrows * 7;
    int cblk = (rows + 3) / 4;
    float* out = (float*)d_out;
    gather_out<<<cblk, 256, 0, stream>>>(ci, g, bfv, out, out + (size_t)rows * 128,
                                         nrows, rows);
}

// Round 2
// 149.888 us; speedup vs baseline: 1.6318x; 1.6318x over previous
//
#include <hip/hip_runtime.h>
#include <stdint.h>

typedef short bf16x8 __attribute__((ext_vector_type(8)));
typedef float f32x4  __attribute__((ext_vector_type(4)));

__device__ __forceinline__ unsigned short f2bf(float f) {
    unsigned int u = __float_as_uint(f);
    u += 0x7FFFu + ((u >> 16) & 1u);
    return (unsigned short)(u >> 16);
}
__device__ __forceinline__ float bf2f(unsigned short h) {
    return __uint_as_float(((unsigned int)h) << 16);
}

// ---- kernel A: fold W1f = w1@wf, W2f = w2@wf (store transposed bf16), cb = b@wf ----
__global__ void fuse_weights(const float* __restrict__ w1, const float* __restrict__ b1,
                             const float* __restrict__ w2, const float* __restrict__ b2,
                             const float* __restrict__ wf,
                             unsigned short* __restrict__ wcT,  // [2][128 cols][128 k]
                             float* __restrict__ cb)            // [2][128]
{
    int mat = blockIdx.x / 129;
    int kk  = blockIdx.x % 129;
    int c   = threadIdx.x;
    const float* w = (mat == 0) ? w1 : w2;
    const float* b = (mat == 0) ? b1 : b2;
    float acc = 0.f;
    if (kk < 128) {
        #pragma unroll 8
        for (int j = 0; j < 128; ++j) acc += w[kk * 128 + j] * wf[j * 128 + c];
        wcT[mat * 16384 + c * 128 + kk] = f2bf(acc);
    } else {
        #pragma unroll 8
        for (int j = 0; j < 128; ++j) acc += b[j] * wf[j * 128 + c];
        cb[mat * 128 + c] = acc;
    }
}

// ---- kernel B: g[mat] = x @ Wc[mat] + cb[mat] -> bf16 [2][nrows][128] ----
// 64 rows per wave (4 rowtiles of 16): 16 MFMAs per 4 wcT fragment loads.
//   A-frag (wcT): lane l holds A[wcol=(l&15)][k=(l>>4)*8+i]
//   B-frag (x):   lane l holds B[k][xrow=(l&15)]
//   D: col(lane&15)=xrow, row((lane>>4)*4+reg)=wcol
#define WAVE_ROWS 64
__global__ __launch_bounds__(256) void gemm_g(
    const float* __restrict__ x, const unsigned short* __restrict__ wcT,
    const float* __restrict__ cb, unsigned short* __restrict__ g, int nrows)
{
    int lane = threadIdx.x & 63;
    int wid  = threadIdx.x >> 6;
    int r0   = (blockIdx.x * 4 + wid) * WAVE_ROWS;
    if (r0 >= nrows) return;
    int lrow = lane & 15;
    int kg   = lane >> 4;

    bf16x8 xf[4][4];   // [rowtile][kstep]
    #pragma unroll
    for (int t = 0; t < 4; ++t) {
        int row = r0 + t * 16 + lrow;
        bool v  = row < nrows;
        #pragma unroll
        for (int ks = 0; ks < 4; ++ks) {
            int k0 = ks * 32 + kg * 8;
            float4 p0 = v ? *(const float4*)(x + (size_t)row * 128 + k0)     : float4{0,0,0,0};
            float4 p1 = v ? *(const float4*)(x + (size_t)row * 128 + k0 + 4) : float4{0,0,0,0};
            bf16x8 f;
            f[0] = (short)f2bf(p0.x); f[1] = (short)f2bf(p0.y);
            f[2] = (short)f2bf(p0.z); f[3] = (short)f2bf(p0.w);
            f[4] = (short)f2bf(p1.x); f[5] = (short)f2bf(p1.y);
            f[6] = (short)f2bf(p1.z); f[7] = (short)f2bf(p1.w);
            xf[t][ks] = f;
        }
    }

    #pragma unroll
    for (int mat = 0; mat < 2; ++mat) {
        unsigned short* gm = g + (size_t)mat * nrows * 128;
        const unsigned short* wT = wcT + mat * 16384;
        #pragma unroll 2
        for (int c = 0; c < 8; ++c) {
            bf16x8 wfr[4];
            const unsigned short* wb = wT + (size_t)(c * 16 + lrow) * 128 + kg * 8;
            #pragma unroll
            for (int ks = 0; ks < 4; ++ks)
                wfr[ks] = *(const bf16x8*)(wb + ks * 32);
            f32x4 acc[4];
            #pragma unroll
            for (int t = 0; t < 4; ++t) acc[t] = f32x4{0,0,0,0};
            #pragma unroll
            for (int ks = 0; ks < 4; ++ks) {
                #pragma unroll
                for (int t = 0; t < 4; ++t)
                    acc[t] = __builtin_amdgcn_mfma_f32_16x16x32_bf16(wfr[ks], xf[t][ks], acc[t], 0,0,0);
            }
            float4 bias = *(const float4*)(cb + mat * 128 + c * 16 + kg * 4);
            #pragma unroll
            for (int t = 0; t < 4; ++t) {
                int xrow = r0 + t * 16 + lrow;
                if (xrow < nrows) {
                    ushort4 o;
                    o.x = f2bf(acc[t][0] + bias.x); o.y = f2bf(acc[t][1] + bias.y);
                    o.z = f2bf(acc[t][2] + bias.z); o.w = f2bf(acc[t][3] + bias.w);
                    *(ushort4*)(gm + (size_t)xrow * 128 + c * 16 + kg * 4) = o;
                }
            }
        }
    }
}

// ---- kernel C: one wave per node; 7 output rows, predicated pipelined gathers ----
__global__ __launch_bounds__(256) void gather_out(
    const int* __restrict__ ci, const unsigned short* __restrict__ g,
    const float* __restrict__ bfv, float* __restrict__ out,
    float* __restrict__ maskout, int nnodes)
{
    int n    = (int)((blockIdx.x * blockDim.x + threadIdx.x) >> 6);
    int lane = threadIdx.x & 63;
    if (n >= nnodes) return;

    int civ = ci[n * 8 + (lane & 7)];
    unsigned long long bal = __ballot(civ == -1);
    int cnt = __popcll(bal & 0xFFull);
    int deg = (cnt == 8) ? 0 : (7 - cnt);

    int d = lane * 2;
    float2 bfd = *(const float2*)(bfv + d);
    size_t outbase = (size_t)n * 7 * 128;
    const unsigned short* g2 = g + (size_t)nnodes * 128;

    #pragma unroll
    for (int j = 0; j < 7; ++j) {
        int i0 = __shfl(civ, j);
        int i1 = __shfl(civ, j + 1);
        bool m1 = (j < deg);
        bool m2 = m1 && (deg >= 2);
        // predicated loads: dummy row 0 when masked -> all 14 loads issue unconditionally
        unsigned u0 = *(const unsigned*)(g  + (size_t)(m1 ? i0 : 0) * 128 + d);
        unsigned u1 = *(const unsigned*)(g2 + (size_t)(m2 ? i1 : 0) * 128 + d);
        float s0 = bfd.x, s1 = bfd.y;
        s0 += m1 ? bf2f((unsigned short)(u0 & 0xFFFFu)) : 0.f;
        s1 += m1 ? bf2f((unsigned short)(u0 >> 16))     : 0.f;
        s0 += m2 ? bf2f((unsigned short)(u1 & 0xFFFFu)) : 0.f;
        s1 += m2 ? bf2f((unsigned short)(u1 >> 16))     : 0.f;
        float2 o; o.x = s0; o.y = s1;
        *(float2*)(out + outbase + (size_t)j * 128 + d) = o;
    }
    if (lane < 7) maskout[n * 7 + lane] = (lane < deg) ? 1.0f : 0.0f;
}

extern "C" void kernel_launch(void* const* d_in, const int* in_sizes, int n_in,
                              void* d_out, int out_size, void* d_ws, size_t ws_size,
                              hipStream_t stream) {
    const float* x   = (const float*)d_in[0];
    const float* w1  = (const float*)d_in[1];
    const float* b1  = (const float*)d_in[2];
    const float* w2  = (const float*)d_in[3];
    const float* b2  = (const float*)d_in[4];
    const float* wf  = (const float*)d_in[5];
    const float* bfv = (const float*)d_in[6];
    const int*   ci  = (const int*)d_in[7];

    int nrows = in_sizes[0] / 128;

    size_t gbytes = (size_t)2 * nrows * 128 * 2;
    unsigned short* g   = (unsigned short*)d_ws;
    unsigned short* wcT = (unsigned short*)((char*)d_ws + ((gbytes + 255) & ~(size_t)255));
    float*          cb  = (float*)((char*)wcT + 2 * 128 * 128 * 2);

    fuse_weights<<<2 * 129, 128, 0, stream>>>(w1, b1, w2, b2, wf, wcT, cb);

    int nblk = (nrows + 4 * WAVE_ROWS - 1) / (4 * WAVE_ROWS);
    gemm_g<<<nblk, 256, 0, stream>>>(x, wcT, cb, g, nrows);

    int rows = nrows * 7;
    int cblk = (nrows * 64 + 255) / 256;
    float* out = (float*)d_out;
    gather_out<<<cblk, 256, 0, stream>>>(ci, g, bfv, out, out + (size_t)rows * 128, nrows);
}

// Round 3
// 123.135 us; speedup vs baseline: 1.9863x; 1.2173x over previous
//
#include <hip/hip_runtime.h>
#include <stdint.h>

typedef short bf16x8 __attribute__((ext_vector_type(8)));
typedef float f32x4  __attribute__((ext_vector_type(4)));
typedef float f32x2  __attribute__((ext_vector_type(2)));

__device__ __forceinline__ unsigned short f2bf(float f) {
    unsigned int u = __float_as_uint(f);
    u += 0x7FFFu + ((u >> 16) & 1u);
    return (unsigned short)(u >> 16);
}
__device__ __forceinline__ float bf2f(unsigned short h) {
    return __uint_as_float(((unsigned int)h) << 16);
}

// ---- kernel A: fold W1f = w1@wf, W2f = w2@wf (store transposed bf16), cb = b@wf ----
__global__ void fuse_weights(const float* __restrict__ w1, const float* __restrict__ b1,
                             const float* __restrict__ w2, const float* __restrict__ b2,
                             const float* __restrict__ wf,
                             unsigned short* __restrict__ wcT,  // [2][128 cols][128 k]
                             float* __restrict__ cb)            // [2][128]
{
    int mat = blockIdx.x / 129;
    int kk  = blockIdx.x % 129;
    int c   = threadIdx.x;
    const float* w = (mat == 0) ? w1 : w2;
    const float* b = (mat == 0) ? b1 : b2;
    float acc = 0.f;
    if (kk < 128) {
        #pragma unroll 8
        for (int j = 0; j < 128; ++j) acc += w[kk * 128 + j] * wf[j * 128 + c];
        wcT[mat * 16384 + c * 128 + kk] = f2bf(acc);
    } else {
        #pragma unroll 8
        for (int j = 0; j < 128; ++j) acc += b[j] * wf[j * 128 + c];
        cb[mat * 128 + c] = acc;
    }
}

// ---- kernel B: g[mat] = x @ Wc[mat] + cb[mat] -> bf16 [2][nrows][128] ----
#define WAVE_ROWS 64
__global__ __launch_bounds__(256) void gemm_g(
    const float* __restrict__ x, const unsigned short* __restrict__ wcT,
    const float* __restrict__ cb, unsigned short* __restrict__ g, int nrows)
{
    int lane = threadIdx.x & 63;
    int wid  = threadIdx.x >> 6;
    int r0   = (blockIdx.x * 4 + wid) * WAVE_ROWS;
    if (r0 >= nrows) return;
    int lrow = lane & 15;
    int kg   = lane >> 4;

    bf16x8 xf[4][4];   // [rowtile][kstep]
    #pragma unroll
    for (int t = 0; t < 4; ++t) {
        int row = r0 + t * 16 + lrow;
        bool v  = row < nrows;
        #pragma unroll
        for (int ks = 0; ks < 4; ++ks) {
            int k0 = ks * 32 + kg * 8;
            float4 p0 = v ? *(const float4*)(x + (size_t)row * 128 + k0)     : float4{0,0,0,0};
            float4 p1 = v ? *(const float4*)(x + (size_t)row * 128 + k0 + 4) : float4{0,0,0,0};
            bf16x8 f;
            f[0] = (short)f2bf(p0.x); f[1] = (short)f2bf(p0.y);
            f[2] = (short)f2bf(p0.z); f[3] = (short)f2bf(p0.w);
            f[4] = (short)f2bf(p1.x); f[5] = (short)f2bf(p1.y);
            f[6] = (short)f2bf(p1.z); f[7] = (short)f2bf(p1.w);
            xf[t][ks] = f;
        }
    }

    #pragma unroll
    for (int mat = 0; mat < 2; ++mat) {
        unsigned short* gm = g + (size_t)mat * nrows * 128;
        const unsigned short* wT = wcT + mat * 16384;
        #pragma unroll 2
        for (int c = 0; c < 8; ++c) {
            bf16x8 wfr[4];
            const unsigned short* wb = wT + (size_t)(c * 16 + lrow) * 128 + kg * 8;
            #pragma unroll
            for (int ks = 0; ks < 4; ++ks)
                wfr[ks] = *(const bf16x8*)(wb + ks * 32);
            f32x4 acc[4];
            #pragma unroll
            for (int t = 0; t < 4; ++t) acc[t] = f32x4{0,0,0,0};
            #pragma unroll
            for (int ks = 0; ks < 4; ++ks) {
                #pragma unroll
                for (int t = 0; t < 4; ++t)
                    acc[t] = __builtin_amdgcn_mfma_f32_16x16x32_bf16(wfr[ks], xf[t][ks], acc[t], 0,0,0);
            }
            float4 bias = *(const float4*)(cb + mat * 128 + c * 16 + kg * 4);
            #pragma unroll
            for (int t = 0; t < 4; ++t) {
                int xrow = r0 + t * 16 + lrow;
                if (xrow < nrows) {
                    ushort4 o;
                    o.x = f2bf(acc[t][0] + bias.x); o.y = f2bf(acc[t][1] + bias.y);
                    o.z = f2bf(acc[t][2] + bias.z); o.w = f2bf(acc[t][3] + bias.w);
                    *(ushort4*)(gm + (size_t)xrow * 128 + c * 16 + kg * 4) = o;
                }
            }
        }
    }
}

// ---- kernel C: one wave per node. Load phase (uniform-deg skipped, all in flight),
//      then branch-free consume, non-temporal stores. ----
__global__ __launch_bounds__(256) void gather_out(
    const int* __restrict__ ci, const unsigned short* __restrict__ g,
    const float* __restrict__ bfv, float* __restrict__ out,
    float* __restrict__ maskout, int nnodes)
{
    int n    = (int)((blockIdx.x * blockDim.x + threadIdx.x) >> 6);
    int lane = threadIdx.x & 63;
    if (n >= nnodes) return;

    int civ = ci[n * 8 + (lane & 7)];
    unsigned long long bal = __ballot(civ == -1);
    int cnt = __popcll(bal & 0xFFull);
    int deg = (cnt == 8) ? 0 : (7 - cnt);     // wave-uniform

    int d = lane * 2;
    float2 bfd = *(const float2*)(bfv + d);
    const unsigned short* g1 = g;
    const unsigned short* g2 = g + (size_t)nnodes * 128;

    // ---- load phase: g1 rows civ[0..deg-1]; g2 rows civ[1..deg] (iff deg>=2).
    // untaken -> 0 bits == {0.0bf16, 0.0bf16}; uniform conditions -> cheap skip.
    unsigned ua[7], ub[7];
    #pragma unroll
    for (int k = 0; k < 7; ++k) {
        int i = __shfl(civ, k);
        ua[k] = (k < deg) ? *(const unsigned*)(g1 + (size_t)i * 128 + d) : 0u;
    }
    bool two = (deg >= 2);
    #pragma unroll
    for (int k = 1; k < 8; ++k) {
        int i = __shfl(civ, k);
        ub[k - 1] = (two && k <= deg) ? *(const unsigned*)(g2 + (size_t)i * 128 + d) : 0u;
    }

    // ---- consume + store phase (branch-free adds; zeros are no-ops) ----
    size_t outbase = (size_t)n * 7 * 128;
    #pragma unroll
    for (int j = 0; j < 7; ++j) {
        float s0 = bfd.x + bf2f((unsigned short)(ua[j] & 0xFFFFu))
                         + bf2f((unsigned short)(ub[j] & 0xFFFFu));
        float s1 = bfd.y + bf2f((unsigned short)(ua[j] >> 16))
                         + bf2f((unsigned short)(ub[j] >> 16));
        f32x2 o; o[0] = s0; o[1] = s1;
        __builtin_nontemporal_store(o, (f32x2*)(out + outbase + (size_t)j * 128 + d));
    }
    if (lane < 7)
        __builtin_nontemporal_store((lane < deg) ? 1.0f : 0.0f, maskout + n * 7 + lane);
}

extern "C" void kernel_launch(void* const* d_in, const int* in_sizes, int n_in,
                              void* d_out, int out_size, void* d_ws, size_t ws_size,
                              hipStream_t stream) {
    const float* x   = (const float*)d_in[0];
    const float* w1  = (const float*)d_in[1];
    const float* b1  = (const float*)d_in[2];
    const float* w2  = (const float*)d_in[3];
    const float* b2  = (const float*)d_in[4];
    const float* wf  = (const float*)d_in[5];
    const float* bfv = (const float*)d_in[6];
    const int*   ci  = (const int*)d_in[7];

    int nrows = in_sizes[0] / 128;

    size_t gbytes = (size_t)2 * nrows * 128 * 2;
    unsigned short* g   = (unsigned short*)d_ws;
    unsigned short* wcT = (unsigned short*)((char*)d_ws + ((gbytes + 255) & ~(size_t)255));
    float*          cb  = (float*)((char*)wcT + 2 * 128 * 128 * 2);

    fuse_weights<<<2 * 129, 128, 0, stream>>>(w1, b1, w2, b2, wf, wcT, cb);

    int nblk = (nrows + 4 * WAVE_ROWS - 1) / (4 * WAVE_ROWS);
    gemm_g<<<nblk, 256, 0, stream>>>(x, wcT, cb, g, nrows);

    int rows = nrows * 7;
    int cblk = (nrows * 64 + 255) / 256;
    float* out = (float*)d_out;
    gather_out<<<cblk, 256, 0, stream>>>(ci, g, bfv, out, out + (size_t)rows * 128, nrows);
}